// Round 23
// baseline (72.603 us; speedup 1.0000x reference)
//
#include <hip/hip_runtime.h>

// FilterInitializerLinear: conv3x3(512->512, pad1) on (192,512,22,22) fp32,
// PrRoIPool 4x4 per (image,seq) roi, mean over 3 images, /(C*16).
// KEY ALGEBRA: pool FIRST (both ops linear):
//   out[s,co,pq] = (sum_K W[co,K] * G[s,K,pq] + b[co]*Sy[p]*Sx[q]) / (3*512*16)
//   G[ci,ky,kx,p,q] = sum_{u,v} wy_shift[ky][p][u] * wx_shift[kx][q][v] * F[ci][u][v]
// Round-22: (1) pool threads own a p-PAIR -- adjacent p's share f32x2 weight
// loads: 1 data b64 + 3 broadcast b64 per 12 FMA (was 4 LDS / 6 FMA); data
// redundancy 4x -> 2x; cross-vh reduce via LDS scratch on the dead tile;
// Gb stores spread over vsub. (2) Opart in bf16 (halves partial traffic).

#define NIMG 192
#define CCH 512
#define FH 22
#define FW 22
#define SPATIAL 484
#define KDIM 4608          // pos*512 + ci
#define NDIM 1024          // s*16 + p*4 + q
#define KQ 8               // K-split factor in GEMM
#define KSEG 576           // KDIM / KQ (9 chunks of 64)
#define CISTRIDE 1968      // per-ci LDS bytes (1936 + 32 pad)
#define POOLBLKS 2048      // 64 s x 32 ciq

typedef __bf16 bf16;
typedef __bf16 bf16x2 __attribute__((ext_vector_type(2)));
typedef __bf16 bf16x4 __attribute__((ext_vector_type(4)));
typedef __bf16 bf16x8 __attribute__((ext_vector_type(8)));
typedef float f32x2 __attribute__((ext_vector_type(2)));
typedef float f32x4 __attribute__((ext_vector_type(4)));

#define GLOBAL_AS __attribute__((address_space(1)))
#define LDS_AS __attribute__((address_space(3)))

__device__ __forceinline__ void gload_lds16(const void* g, void* l) {
  __builtin_amdgcn_global_load_lds((GLOBAL_AS const void*)g, (LDS_AS void*)l, 16, 0, 0);
}

// raw barriers: LBAR orders LDS only (vmcnt stays outstanding); FBAR drains all
#define LBAR()                                                   \
  do {                                                           \
    asm volatile("s_waitcnt lgkmcnt(0)" ::: "memory");           \
    __builtin_amdgcn_s_barrier();                                \
  } while (0)
#define FBAR()                                                   \
  do {                                                           \
    asm volatile("s_waitcnt vmcnt(0) lgkmcnt(0)" ::: "memory");  \
    __builtin_amdgcn_s_barrier();                                \
  } while (0)

// Extended read range [r0, r1] for one axis (fp-identical everywhere).
__device__ __forceinline__ void axis_range(float a0, float aw, int& r0, int& r1) {
  const float scale = 1.f / 16.f;
  float s1 = a0 * scale;
  float s2 = (a0 + aw) * scale;
  float bl = (s2 - s1) * 0.25f;
  float endv = (s1 + 3 * bl) + bl;
  int c0 = max(0, (int)floorf(s1));
  int c1 = min(21, (int)floorf(endv) + 1);
  r0 = max(0, c0 - 1);
  r1 = min(21, c1 + 1);
}

// Sum of pooling weights for one (axis, bin) -- for the bias term.
__device__ __forceinline__ float axis_sum(float a0, float aw, int bin) {
  const float scale = 1.f / 16.f;
  float s1 = a0 * scale;
  float s2 = (a0 + aw) * scale;
  float blen = (s2 - s1) * 0.25f;
  float start = s1 + bin * blen;
  float end = start + blen;
  float inv = 1.0f / blen;
  float S = 0.f;
  int s0i = (int)floorf(start);
  for (int kk = 0; kk < 6; ++kk) {
    int cell = s0i + kk;
    float cf = (float)cell;
    float a1 = fmaxf(start, cf);
    float a2 = fmaxf(fminf(end, cf + 1.f), a1);
    float alpha = a1 - cf, lim = a2 - cf;
    float f0 = (lim - 0.5f * lim * lim) - (alpha - 0.5f * alpha * alpha);
    float f1 = 0.5f * lim * lim - 0.5f * alpha * alpha;
    if (cell >= 0 && cell < 22) S += f0 * inv;
    if (cell + 1 >= 0 && cell + 1 < 22) S += f1 * inv;
  }
  return S;
}

// ---- pool_feat (+ fused wtrans): separable PrRoI pooling DIRECT from fp32
// NCHW feat, summed over 3 images in registers -> Gb[N][K] bf16.
// Blocks [0, 2048): pool. 16-ci tile + 3 table sets = 37.8KB -> 4 blocks/CU.
// 256 threads = 4 waves: wave = (ph 2, vh 2); lane = ci16(16) + 16*vsub(4).
// Thread owns p-pair {2ph, 2ph+1}; v-groups = vh*4 + vsub (8-way).
// Per u: 1 data b64 + 3 wave-uniform f32x2 weight loads -> 12 FMA.
// Cross-vh reduce via LDS scratch overlaid on dead tile; stores spread by vsub.
// Blocks [2048, 2560): conv_w (co,ci,3,3) -> Wb[co][pos][ci] bf16.
__global__ __launch_bounds__(256, 4) void pool_feat_kernel(
    const float* __restrict__ feat, const float* __restrict__ bb,
    const float* __restrict__ cw, bf16* __restrict__ Wb,
    bf16* __restrict__ Gb) {
  __shared__ __align__(16) char tileb[16 * CISTRIDE];   // 31,488 B
  __shared__ float wyl3[3 * 264];   // per-img shifted y tables
  __shared__ float wxl3[3 * 264];   // per-img shifted x tables
  int t = threadIdx.x;
  if (blockIdx.x >= POOLBLKS) {              // fused wtrans
    int co = blockIdx.x - POOLBLKS;
    float* lw = (float*)tileb;               // 18,432 B scratch
    const float* src = cw + (long)co * CCH * 9;
    #pragma unroll
    for (int k = 0; k < 18; ++k) lw[t + 256 * k] = src[t + 256 * k];
    __syncthreads();
    bf16* dst = Wb + (long)co * 9 * CCH;
    #pragma unroll
    for (int k = 0; k < 18; ++k) {
      int f = t + 256 * k;
      int pos = f >> 9;
      int ci = f & 511;
      dst[f] = (bf16)lw[ci * 9 + pos];
    }
    return;
  }
  int s = blockIdx.x >> 5;
  int ciq = blockIdx.x & 31;
  int w = t >> 6;
  int ph = w >> 1;                // p-pair index: p = 2ph, 2ph+1
  int vh = w & 1;                 // v-half (cross-wave)
  int lane = t & 63;
  int ci16 = lane & 15;
  int vsub = lane >> 4;           // v-subgroup within half
  int vg8 = vh * 4 + vsub;        // 8-way v-group

  int yr0a[3], yr1a[3], xr0a[3], xr1a[3];
  #pragma unroll
  for (int i = 0; i < 3; ++i) {
    int n = i * 64 + s;
    axis_range(bb[n * 4 + 1], bb[n * 4 + 3], yr0a[i], yr1a[i]);
    axis_range(bb[n * 4 + 0], bb[n * 4 + 2], xr0a[i], xr1a[i]);
  }

  f32x4 A0[9], A1[9];   // [pos] over q, for p0=2ph and p1=2ph+1
  #pragma unroll
  for (int a = 0; a < 9; ++a) {
    A0[a] = (f32x4){0.f, 0.f, 0.f, 0.f};
    A1[a] = (f32x4){0.f, 0.f, 0.f, 0.f};
  }
  const float* tf = (const float*)tileb;

  auto STAGE = [&](int img) {
    int n = img * 64 + s;
    int start16 = (yr0a[img] * 88) & ~15;
    int end16 = ((yr1a[img] + 1) * 88 + 15) & ~15;   // <= 1936
    int cpi = (end16 - start16 + 1023) >> 10;        // 1 or 2
    const float* fpl0 = feat + ((long)n * CCH + ciq * 16) * SPATIAL;
    for (int k = w; k < 16 * cpi; k += 4) {          // wave-uniform k
      int ci = (cpi == 2) ? (k >> 1) : k;
      int c = (cpi == 2) ? (k & 1) : 0;
      int cs = (c == cpi - 1) ? end16 - 1024 : start16;
      if (cs < 0) cs = 0;                            // short-run clamp
      gload_lds16((const char*)(fpl0 + (long)ci * SPATIAL) + cs + lane * 16,
                  tileb + ci * CISTRIDE + cs + lane * 16);
    }
  };

  auto COMPUTE = [&](int img) {
    int yr0 = yr0a[img], yr1 = yr1a[img];
    int vbase = xr0a[img] & ~1;
    int npairs = ((xr1a[img] - vbase) >> 1) + 1;
    const float* wy = wyl3 + img * 264;
    const f32x4* wx = (const f32x4*)(wxl3 + img * 264);
    const f32x2* pl2 = (const f32x2*)(tf + ci16 * (CISTRIDE / 4));
    for (int j = vg8; j < npairs; j += 8) {
      int vg = vbase + 2 * j;
      float a00 = 0.f, a01 = 0.f, a10 = 0.f, a11 = 0.f, a20 = 0.f, a21 = 0.f;
      float b00 = 0.f, b01 = 0.f, b10 = 0.f, b11 = 0.f, b20 = 0.f, b21 = 0.f;
      for (int u = yr0; u <= yr1; ++u) {
        f32x2 f = pl2[(u * FW + vg) >> 1];          // even offset -> 8B aligned
        // weight pairs for (p0, p1): adjacent in table -> single f32x2 loads
        f32x2 wk0 = *(const f32x2*)(wy + u * 4 + 2 * ph);
        f32x2 wk1 = *(const f32x2*)(wy + (22 + u) * 4 + 2 * ph);
        f32x2 wk2 = *(const f32x2*)(wy + (44 + u) * 4 + 2 * ph);
        a00 = fmaf(wk0[0], f[0], a00); a01 = fmaf(wk0[0], f[1], a01);
        a10 = fmaf(wk1[0], f[0], a10); a11 = fmaf(wk1[0], f[1], a11);
        a20 = fmaf(wk2[0], f[0], a20); a21 = fmaf(wk2[0], f[1], a21);
        b00 = fmaf(wk0[1], f[0], b00); b01 = fmaf(wk0[1], f[1], b01);
        b10 = fmaf(wk1[1], f[0], b10); b11 = fmaf(wk1[1], f[1], b11);
        b20 = fmaf(wk2[1], f[0], b20); b21 = fmaf(wk2[1], f[1], b21);
      }
      #pragma unroll
      for (int kx = 0; kx < 3; ++kx) {
        f32x4 wx0 = wx[kx * 22 + vg];
        f32x4 wx1 = wx[kx * 22 + vg + 1];           // zero outside box
        A0[kx] += wx0 * a00 + wx1 * a01;
        A0[3 + kx] += wx0 * a10 + wx1 * a11;
        A0[6 + kx] += wx0 * a20 + wx1 * a21;
        A1[kx] += wx0 * b00 + wx1 * b01;
        A1[3 + kx] += wx0 * b10 + wx1 * b11;
        A1[6 + kx] += wx0 * b20 + wx1 * b21;
      }
    }
  };

  STAGE(0);                       // in flight during table build
  for (int idx = t; idx < 1584; idx += 256)
    (idx < 792 ? wyl3[idx] : wxl3[idx - 792]) = 0.f;
  LBAR();                         // zeros visible; staging stays outstanding
  if (t < 24) {
    int img = t >> 3;
    int axis = (t >> 2) & 1;
    int bin = t & 3;
    int n = img * 64 + s;
    const float scale = 1.f / 16.f;
    float a0 = axis ? bb[n * 4 + 0] : bb[n * 4 + 1];
    float aw = axis ? bb[n * 4 + 2] : bb[n * 4 + 3];
    float s1 = a0 * scale;
    float s2 = (a0 + aw) * scale;
    float blen = (s2 - s1) * 0.25f;
    float start = s1 + bin * blen;
    float end = start + blen;
    float inv = 1.0f / blen;
    float* tbl = (axis ? wxl3 : wyl3) + img * 264;
    int s0i = (int)floorf(start);
    for (int kk = 0; kk < 6; ++kk) {
      int cell = s0i + kk;
      float cf = (float)cell;
      float a1 = fmaxf(start, cf);
      float a2 = fmaxf(fminf(end, cf + 1.f), a1);
      float alpha = a1 - cf, lim = a2 - cf;
      float f0 = (lim - 0.5f * lim * lim) - (alpha - 0.5f * alpha * alpha);
      float f1 = 0.5f * lim * lim - 0.5f * alpha * alpha;
      if (cell >= 0 && cell < 22) {
        float wv_ = f0 * inv;
        #pragma unroll
        for (int ky = 0; ky < 3; ++ky) {
          int u = cell + ky - 1;
          if (u >= 0 && u < 22) tbl[(ky * 22 + u) * 4 + bin] += wv_;
        }
      }
      if (cell + 1 >= 0 && cell + 1 < 22) {
        float wv_ = f1 * inv;
        #pragma unroll
        for (int ky = 0; ky < 3; ++ky) {
          int u = cell + ky;
          if (u >= 0 && u < 22) tbl[(ky * 22 + u) * 4 + bin] += wv_;
        }
      }
    }
  }
  FBAR();                         // tables ready + stage(0) landed
  COMPUTE(0);
  #pragma unroll 1
  for (int img = 1; img < 3; ++img) {
    LBAR();                       // prev compute's LDS reads done
    STAGE(img);
    FBAR();                       // staging landed
    COMPUTE(img);
  }

  // reduce over vsub in-wave (lane bits 4 and 5)
  #pragma unroll
  for (int pos = 0; pos < 9; ++pos) {
    #pragma unroll
    for (int q = 0; q < 4; ++q) {
      A0[pos][q] += __shfl_xor(A0[pos][q], 16);
      A0[pos][q] += __shfl_xor(A0[pos][q], 32);
      A1[pos][q] += __shfl_xor(A1[pos][q], 16);
      A1[pos][q] += __shfl_xor(A1[pos][q], 32);
    }
  }
  // cross-vh reduce via scratch overlaid on the (dead) tile
  __syncthreads();
  f32x4* scr = (f32x4*)tileb;     // [ph*16+ci16][18]
  if (vh == 1 && vsub == 0) {
    int base = (ph * 16 + ci16) * 18;
    #pragma unroll
    for (int pos = 0; pos < 9; ++pos) {
      scr[base + pos] = A0[pos];
      scr[base + 9 + pos] = A1[pos];
    }
  }
  __syncthreads();
  if (vh == 0) {
    int base = (ph * 16 + ci16) * 18;
    int ci = ciq * 16 + ci16;
    int p0 = ph * 2;
    #pragma unroll
    for (int pos = 0; pos < 9; ++pos) {
      if ((pos & 3) != vsub) continue;   // stores spread over vsub groups
      f32x4 v0 = A0[pos] + scr[base + pos];
      f32x4 v1 = A1[pos] + scr[base + 9 + pos];
      #pragma unroll
      for (int q = 0; q < 4; ++q) {
        Gb[(long)(s * 16 + p0 * 4 + q) * KDIM + pos * CCH + ci] = (bf16)v0[q];
        Gb[(long)(s * 16 + (p0 + 1) * 4 + q) * KDIM + pos * CCH + ci] = (bf16)v1[q];
      }
    }
  }
}

// ---- gemm: Opart[kq][co 512][n 1024] (bf16) = W[co][k]*Gb[n][k] over seg.
// 512 blocks = 4 mt x 16 nt x 8 kq (2/CU); 128co x 64n tile, 4 waves, BK=64,
// 9 chunks, XOR swizzle.
__global__ __launch_bounds__(256, 2) void gemm_kernel(const bf16* __restrict__ Wb,
                                                      const bf16* __restrict__ Gb,
                                                      bf16* __restrict__ Opart) {
  __shared__ __align__(16) bf16 As[128 * 64];
  __shared__ __align__(16) bf16 Bs[64 * 64];
  int bid = blockIdx.x;
  int kq = bid & 7;
  int nt = (bid >> 3) & 15;
  int mt = bid >> 7;
  int co0 = mt << 7;
  int n0 = nt << 6;
  int kbase = kq * KSEG;

  int tid = threadIdx.x;
  int wv = tid >> 6, l = tid & 63;
  int wm = wv >> 1, wn = wv & 1;
  int lrow = l >> 3;
  int cg8 = ((l & 7) ^ lrow) << 3;

  long aOff[4], bOff[2];
  #pragma unroll
  for (int j = 0; j < 4; ++j) {
    int row = j * 32 + wv * 8 + lrow;
    aOff[j] = (long)(co0 + row) * KDIM + kbase + cg8;
  }
  #pragma unroll
  for (int j = 0; j < 2; ++j) {
    int row = j * 32 + wv * 8 + lrow;
    bOff[j] = (long)(n0 + row) * KDIM + kbase + cg8;
  }

  const f32x4 vz = {0.f, 0.f, 0.f, 0.f};
  f32x4 acc[4][2];
  #pragma unroll
  for (int a = 0; a < 4; ++a)
    #pragma unroll
    for (int b = 0; b < 2; ++b) acc[a][b] = vz;

  for (int c = 0; c < 9; ++c) {
    long sh = c * 64;
    #pragma unroll
    for (int j = 0; j < 4; ++j)
      gload_lds16(Wb + aOff[j] + sh, (char*)As + (j * 32 + wv * 8) * 128);
    #pragma unroll
    for (int j = 0; j < 2; ++j)
      gload_lds16(Gb + bOff[j] + sh, (char*)Bs + (j * 32 + wv * 8) * 128);
    __syncthreads();
    bf16x8 af[2][4], bfv[2][2];
    #pragma unroll
    for (int kk = 0; kk < 2; ++kk) {
      #pragma unroll
      for (int i = 0; i < 4; ++i) {
        int rowa = wm * 64 + i * 16 + (l & 15);
        int offa = rowa * 128 + kk * 64 + ((l >> 4) * 16);
        offa ^= (rowa & 7) << 4;
        af[kk][i] = *(const bf16x8*)((const char*)As + offa);
      }
      #pragma unroll
      for (int i = 0; i < 2; ++i) {
        int rowb = wn * 32 + i * 16 + (l & 15);
        int offb = rowb * 128 + kk * 64 + ((l >> 4) * 16);
        offb ^= (rowb & 7) << 4;
        bfv[kk][i] = *(const bf16x8*)((const char*)Bs + offb);
      }
    }
    #pragma unroll
    for (int kk = 0; kk < 2; ++kk)
      #pragma unroll
      for (int mi = 0; mi < 4; ++mi)
        #pragma unroll
        for (int nj = 0; nj < 2; ++nj)
          acc[mi][nj] = __builtin_amdgcn_mfma_f32_16x16x32_bf16(
              af[kk][mi], bfv[kk][nj], acc[mi][nj], 0, 0, 0);
    __syncthreads();
  }

  // C/D layout: col=lane&15 (n), row=(lane>>4)*4+reg (co)
  bf16* op = Opart + (long)kq * CCH * NDIM;
  #pragma unroll
  for (int nj = 0; nj < 2; ++nj) {
    int nn = n0 + wn * 32 + nj * 16 + (l & 15);
    #pragma unroll
    for (int mi = 0; mi < 4; ++mi) {
      #pragma unroll
      for (int rr = 0; rr < 4; ++rr) {
        int co = co0 + wm * 64 + mi * 16 + (l >> 4) * 4 + rr;
        op[(long)co * NDIM + nn] = (bf16)acc[mi][nj][rr];
      }
    }
  }
}

// ---- epilogue: out[s][co][pq] = (sum_kq Opart + b[co]*BF(s,p,q)) * fin
// Each block covers ONE s; 16 threads build BF[16] in LDS once.
__global__ __launch_bounds__(256) void epi_kernel(const bf16* __restrict__ Opart,
                                                  const float* __restrict__ bb,
                                                  const float* __restrict__ cb,
                                                  float* __restrict__ out) {
  __shared__ float bfl[16];
  int bid = blockIdx.x;
  int t = threadIdx.x;
  int s = bid >> 3;                          // 8 blocks per s
  if (t < 16) {
    int p = t >> 2;
    int q = t & 3;
    float acc = 0.f;
    #pragma unroll
    for (int i = 0; i < 3; ++i) {
      int n = i * 64 + s;
      acc += axis_sum(bb[n * 4 + 1], bb[n * 4 + 3], p) *
             axis_sum(bb[n * 4 + 0], bb[n * 4 + 2], q);
    }
    bfl[t] = acc;
  }
  __syncthreads();
  int base = (bid * 256 + t) * 4;            // = s*8192 + co*16 + p*4
  int co = (base >> 4) & 511;
  int p = (base >> 2) & 3;
  long osrc = (long)co * NDIM + s * 16 + p * 4;
  f32x4 v = {0.f, 0.f, 0.f, 0.f};
  #pragma unroll
  for (int kq = 0; kq < KQ; ++kq) {
    bf16x4 o = *(const bf16x4*)(Opart + (long)kq * CCH * NDIM + osrc);
    #pragma unroll
    for (int j = 0; j < 4; ++j) v[j] += (float)o[j];
  }
  f32x4 bf4 = {bfl[p * 4 + 0], bfl[p * 4 + 1], bfl[p * 4 + 2], bfl[p * 4 + 3]};
  const float fin = 1.f / (3.f * 512.f * 16.f);
  v = (v + cb[co] * bf4) * fin;
  *(f32x4*)(out + base) = v;
}

extern "C" void kernel_launch(void* const* d_in, const int* in_sizes, int n_in,
                              void* d_out, int out_size, void* d_ws, size_t ws_size,
                              hipStream_t stream) {
  const float* feat = (const float*)d_in[0];
  const float* bb = (const float*)d_in[1];
  const float* cw = (const float*)d_in[2];
  const float* cb = (const float*)d_in[3];
  float* out = (float*)d_out;

  const size_t WB_BYTES = (size_t)CCH * 9 * CCH * 2;            //   4,718,592
  const size_t GB_BYTES = (size_t)NDIM * KDIM * 2;              //   9,437,184
  const size_t OP_BYTES = (size_t)KQ * CCH * NDIM * 2;          //   8,388,608
  if (ws_size < WB_BYTES + GB_BYTES + OP_BYTES) return;

  char* ws = (char*)d_ws;
  bf16* Wb = (bf16*)ws;
  bf16* Gb = (bf16*)(ws + WB_BYTES);
  bf16* Opart = (bf16*)(ws + WB_BYTES + GB_BYTES);

  hipLaunchKernelGGL(pool_feat_kernel, dim3(POOLBLKS + CCH), dim3(256), 0, stream,
                     feat, bb, cw, Wb, Gb);
  hipLaunchKernelGGL(gemm_kernel, dim3(512), dim3(256), 0, stream, Wb, Gb, Opart);
  hipLaunchKernelGGL(epi_kernel, dim3(512), dim3(256), 0, stream, Opart, bb, cb, out);
}

// Round 24
// 67.394 us; speedup vs baseline: 1.0773x; 1.0773x over previous
//
#include <hip/hip_runtime.h>

// FilterInitializerLinear: conv3x3(512->512, pad1) on (192,512,22,22) fp32,
// PrRoIPool 4x4 per (image,seq) roi, mean over 3 images, /(C*16).
// KEY ALGEBRA: pool FIRST (both ops linear):
//   out[s,co,pq] = (sum_K W[co,K] * G[s,K,pq] + b[co]*Sy[p]*Sx[q]) / (3*512*16)
//   G[ci,ky,kx,p,q] = sum_{u,v} wy_shift[ky][p][u] * wx_shift[kx][q][v] * F[ci][u][v]
// Round-23: unbundle round-22 -- pool reverted to the proven round-21
// structure (69.8us config); keep ONLY the bf16 Opart (gemm out + epi in),
// which halves the partial round-trip and was numerically free.

#define NIMG 192
#define CCH 512
#define FH 22
#define FW 22
#define SPATIAL 484
#define KDIM 4608          // pos*512 + ci
#define NDIM 1024          // s*16 + p*4 + q
#define KQ 8               // K-split factor in GEMM
#define KSEG 576           // KDIM / KQ (9 chunks of 64)
#define CISTRIDE 1968      // per-ci LDS bytes (1936 + 32 pad)
#define POOLBLKS 2048      // 64 s x 32 ciq

typedef __bf16 bf16;
typedef __bf16 bf16x2 __attribute__((ext_vector_type(2)));
typedef __bf16 bf16x4 __attribute__((ext_vector_type(4)));
typedef __bf16 bf16x8 __attribute__((ext_vector_type(8)));
typedef float f32x2 __attribute__((ext_vector_type(2)));
typedef float f32x4 __attribute__((ext_vector_type(4)));

#define GLOBAL_AS __attribute__((address_space(1)))
#define LDS_AS __attribute__((address_space(3)))

__device__ __forceinline__ void gload_lds16(const void* g, void* l) {
  __builtin_amdgcn_global_load_lds((GLOBAL_AS const void*)g, (LDS_AS void*)l, 16, 0, 0);
}

// raw barriers: LBAR orders LDS only (vmcnt stays outstanding); FBAR drains all
#define LBAR()                                                   \
  do {                                                           \
    asm volatile("s_waitcnt lgkmcnt(0)" ::: "memory");           \
    __builtin_amdgcn_s_barrier();                                \
  } while (0)
#define FBAR()                                                   \
  do {                                                           \
    asm volatile("s_waitcnt vmcnt(0) lgkmcnt(0)" ::: "memory");  \
    __builtin_amdgcn_s_barrier();                                \
  } while (0)

// Extended read range [r0, r1] for one axis (fp-identical everywhere).
__device__ __forceinline__ void axis_range(float a0, float aw, int& r0, int& r1) {
  const float scale = 1.f / 16.f;
  float s1 = a0 * scale;
  float s2 = (a0 + aw) * scale;
  float bl = (s2 - s1) * 0.25f;
  float endv = (s1 + 3 * bl) + bl;
  int c0 = max(0, (int)floorf(s1));
  int c1 = min(21, (int)floorf(endv) + 1);
  r0 = max(0, c0 - 1);
  r1 = min(21, c1 + 1);
}

// Sum of pooling weights for one (axis, bin) -- for the bias term.
__device__ __forceinline__ float axis_sum(float a0, float aw, int bin) {
  const float scale = 1.f / 16.f;
  float s1 = a0 * scale;
  float s2 = (a0 + aw) * scale;
  float blen = (s2 - s1) * 0.25f;
  float start = s1 + bin * blen;
  float end = start + blen;
  float inv = 1.0f / blen;
  float S = 0.f;
  int s0i = (int)floorf(start);
  for (int kk = 0; kk < 6; ++kk) {
    int cell = s0i + kk;
    float cf = (float)cell;
    float a1 = fmaxf(start, cf);
    float a2 = fmaxf(fminf(end, cf + 1.f), a1);
    float alpha = a1 - cf, lim = a2 - cf;
    float f0 = (lim - 0.5f * lim * lim) - (alpha - 0.5f * alpha * alpha);
    float f1 = 0.5f * lim * lim - 0.5f * alpha * alpha;
    if (cell >= 0 && cell < 22) S += f0 * inv;
    if (cell + 1 >= 0 && cell + 1 < 22) S += f1 * inv;
  }
  return S;
}

// ---- pool_feat (+ fused wtrans): separable PrRoI pooling DIRECT from fp32
// NCHW feat, summed over 3 images in registers -> Gb[N][K] bf16.
// Blocks [0, 2048): pool. 16-ci tile + 3 table sets = 37.8KB -> 4 blocks/CU.
// 256 threads = 4 waves (wave = p); lane = ci16(16) + 16*vquarter(4).
// stage(img0) issued before table zero/fill; lgkm-only barrier keeps its
// loads in flight; FBAR before compute drains. Per img 1/2: LBAR, stage,
// FBAR, compute.
// Blocks [2048, 2560): conv_w (co,ci,3,3) -> Wb[co][pos][ci] bf16.
__global__ __launch_bounds__(256, 4) void pool_feat_kernel(
    const float* __restrict__ feat, const float* __restrict__ bb,
    const float* __restrict__ cw, bf16* __restrict__ Wb,
    bf16* __restrict__ Gb) {
  __shared__ __align__(16) char tileb[16 * CISTRIDE];   // 31,488 B
  __shared__ float wyl3[3 * 264];   // per-img shifted y tables
  __shared__ float wxl3[3 * 264];   // per-img shifted x tables
  int t = threadIdx.x;
  if (blockIdx.x >= POOLBLKS) {              // fused wtrans
    int co = blockIdx.x - POOLBLKS;
    float* lw = (float*)tileb;               // 18,432 B scratch
    const float* src = cw + (long)co * CCH * 9;
    #pragma unroll
    for (int k = 0; k < 18; ++k) lw[t + 256 * k] = src[t + 256 * k];
    __syncthreads();
    bf16* dst = Wb + (long)co * 9 * CCH;
    #pragma unroll
    for (int k = 0; k < 18; ++k) {
      int f = t + 256 * k;
      int pos = f >> 9;
      int ci = f & 511;
      dst[f] = (bf16)lw[ci * 9 + pos];
    }
    return;
  }
  int s = blockIdx.x >> 5;
  int ciq = blockIdx.x & 31;
  int p = t >> 6;                 // wave id == p
  int lane = t & 63;
  int ci16 = lane & 15;
  int vq = lane >> 4;             // v-quarter

  int yr0a[3], yr1a[3], xr0a[3], xr1a[3];
  #pragma unroll
  for (int i = 0; i < 3; ++i) {
    int n = i * 64 + s;
    axis_range(bb[n * 4 + 1], bb[n * 4 + 3], yr0a[i], yr1a[i]);
    axis_range(bb[n * 4 + 0], bb[n * 4 + 2], xr0a[i], xr1a[i]);
  }

  f32x4 A[9];   // [pos = ky*3+kx] over q; summed over imgs (this p, vq)
  #pragma unroll
  for (int a = 0; a < 9; ++a) A[a] = (f32x4){0.f, 0.f, 0.f, 0.f};
  const float* tf = (const float*)tileb;

  auto STAGE = [&](int img) {
    int n = img * 64 + s;
    int start16 = (yr0a[img] * 88) & ~15;
    int end16 = ((yr1a[img] + 1) * 88 + 15) & ~15;   // <= 1936
    int cpi = (end16 - start16 + 1023) >> 10;        // 1 or 2
    const float* fpl0 = feat + ((long)n * CCH + ciq * 16) * SPATIAL;
    for (int k = p; k < 16 * cpi; k += 4) {          // wave-uniform k
      int ci = (cpi == 2) ? (k >> 1) : k;
      int c = (cpi == 2) ? (k & 1) : 0;
      int cs = (c == cpi - 1) ? end16 - 1024 : start16;
      if (cs < 0) cs = 0;                            // short-run clamp
      gload_lds16((const char*)(fpl0 + (long)ci * SPATIAL) + cs + lane * 16,
                  tileb + ci * CISTRIDE + cs + lane * 16);
    }
  };

  auto COMPUTE = [&](int img) {
    int yr0 = yr0a[img], yr1 = yr1a[img];
    int vbase = xr0a[img] & ~1;
    int npairs = ((xr1a[img] - vbase) >> 1) + 1;
    const float* wy = wyl3 + img * 264;
    const f32x4* wx = (const f32x4*)(wxl3 + img * 264);
    const f32x2* pl2 = (const f32x2*)(tf + ci16 * (CISTRIDE / 4));
    for (int j = vq; j < npairs; j += 4) {
      int vg = vbase + 2 * j;
      float a00 = 0.f, a01 = 0.f, a10 = 0.f, a11 = 0.f, a20 = 0.f, a21 = 0.f;
      for (int u = yr0; u <= yr1; ++u) {
        f32x2 f = pl2[(u * FW + vg) >> 1];          // even offset -> 8B aligned
        float w0 = wy[u * 4 + p];
        float w1 = wy[(22 + u) * 4 + p];
        float w2 = wy[(44 + u) * 4 + p];
        a00 = fmaf(w0, f[0], a00); a01 = fmaf(w0, f[1], a01);
        a10 = fmaf(w1, f[0], a10); a11 = fmaf(w1, f[1], a11);
        a20 = fmaf(w2, f[0], a20); a21 = fmaf(w2, f[1], a21);
      }
      #pragma unroll
      for (int kx = 0; kx < 3; ++kx) {
        f32x4 wx0 = wx[kx * 22 + vg];
        f32x4 wx1 = wx[kx * 22 + vg + 1];           // zero outside box
        A[kx] += wx0 * a00 + wx1 * a01;
        A[3 + kx] += wx0 * a10 + wx1 * a11;
        A[6 + kx] += wx0 * a20 + wx1 * a21;
      }
    }
  };

  STAGE(0);                       // in flight during table build
  for (int idx = t; idx < 1584; idx += 256)
    (idx < 792 ? wyl3[idx] : wxl3[idx - 792]) = 0.f;
  LBAR();                         // zeros visible; staging stays outstanding
  if (t < 24) {
    int img = t >> 3;
    int axis = (t >> 2) & 1;
    int bin = t & 3;
    int n = img * 64 + s;
    const float scale = 1.f / 16.f;
    float a0 = axis ? bb[n * 4 + 0] : bb[n * 4 + 1];
    float aw = axis ? bb[n * 4 + 2] : bb[n * 4 + 3];
    float s1 = a0 * scale;
    float s2 = (a0 + aw) * scale;
    float blen = (s2 - s1) * 0.25f;
    float start = s1 + bin * blen;
    float end = start + blen;
    float inv = 1.0f / blen;
    float* tbl = (axis ? wxl3 : wyl3) + img * 264;
    int s0i = (int)floorf(start);
    for (int kk = 0; kk < 6; ++kk) {
      int cell = s0i + kk;
      float cf = (float)cell;
      float a1 = fmaxf(start, cf);
      float a2 = fmaxf(fminf(end, cf + 1.f), a1);
      float alpha = a1 - cf, lim = a2 - cf;
      float f0 = (lim - 0.5f * lim * lim) - (alpha - 0.5f * alpha - 0.5f * alpha * alpha + 0.5f * alpha);
      // NOTE: expression must stay fp-identical to reference; use the
      // canonical form below instead (the line above would be wrong).
      f0 = (lim - 0.5f * lim * lim) - (alpha - 0.5f * alpha * alpha);
      float f1 = 0.5f * lim * lim - 0.5f * alpha * alpha;
      if (cell >= 0 && cell < 22) {
        float w = f0 * inv;
        #pragma unroll
        for (int ky = 0; ky < 3; ++ky) {
          int u = cell + ky - 1;
          if (u >= 0 && u < 22) tbl[(ky * 22 + u) * 4 + bin] += w;
        }
      }
      if (cell + 1 >= 0 && cell + 1 < 22) {
        float w = f1 * inv;
        #pragma unroll
        for (int ky = 0; ky < 3; ++ky) {
          int u = cell + ky;
          if (u >= 0 && u < 22) tbl[(ky * 22 + u) * 4 + bin] += w;
        }
      }
    }
  }
  FBAR();                         // tables ready + stage(0) landed
  COMPUTE(0);
  #pragma unroll 1
  for (int img = 1; img < 3; ++img) {
    LBAR();                       // prev compute's LDS reads done
    STAGE(img);
    FBAR();                       // staging landed
    COMPUTE(img);
  }

  // cross-vquarter reduce in-wave (lane bits 4 and 5)
  #pragma unroll
  for (int pos = 0; pos < 9; ++pos) {
    #pragma unroll
    for (int q = 0; q < 4; ++q) {
      A[pos][q] += __shfl_xor(A[pos][q], 16);
      A[pos][q] += __shfl_xor(A[pos][q], 32);
    }
  }
  if (vq == 0) {
    int ci = ciq * 16 + ci16;
    #pragma unroll
    for (int pos = 0; pos < 9; ++pos)
      #pragma unroll
      for (int q = 0; q < 4; ++q)
        Gb[(long)(s * 16 + p * 4 + q) * KDIM + pos * CCH + ci] = (bf16)A[pos][q];
  }
}

// ---- gemm: Opart[kq][co 512][n 1024] (bf16) = W[co][k]*Gb[n][k] over seg.
// 512 blocks = 4 mt x 16 nt x 8 kq (2/CU); 128co x 64n tile, 4 waves, BK=64,
// 9 chunks, XOR swizzle.
__global__ __launch_bounds__(256, 2) void gemm_kernel(const bf16* __restrict__ Wb,
                                                      const bf16* __restrict__ Gb,
                                                      bf16* __restrict__ Opart) {
  __shared__ __align__(16) bf16 As[128 * 64];
  __shared__ __align__(16) bf16 Bs[64 * 64];
  int bid = blockIdx.x;
  int kq = bid & 7;
  int nt = (bid >> 3) & 15;
  int mt = bid >> 7;
  int co0 = mt << 7;
  int n0 = nt << 6;
  int kbase = kq * KSEG;

  int tid = threadIdx.x;
  int wv = tid >> 6, l = tid & 63;
  int wm = wv >> 1, wn = wv & 1;
  int lrow = l >> 3;
  int cg8 = ((l & 7) ^ lrow) << 3;

  long aOff[4], bOff[2];
  #pragma unroll
  for (int j = 0; j < 4; ++j) {
    int row = j * 32 + wv * 8 + lrow;
    aOff[j] = (long)(co0 + row) * KDIM + kbase + cg8;
  }
  #pragma unroll
  for (int j = 0; j < 2; ++j) {
    int row = j * 32 + wv * 8 + lrow;
    bOff[j] = (long)(n0 + row) * KDIM + kbase + cg8;
  }

  const f32x4 vz = {0.f, 0.f, 0.f, 0.f};
  f32x4 acc[4][2];
  #pragma unroll
  for (int a = 0; a < 4; ++a)
    #pragma unroll
    for (int b = 0; b < 2; ++b) acc[a][b] = vz;

  for (int c = 0; c < 9; ++c) {
    long sh = c * 64;
    #pragma unroll
    for (int j = 0; j < 4; ++j)
      gload_lds16(Wb + aOff[j] + sh, (char*)As + (j * 32 + wv * 8) * 128);
    #pragma unroll
    for (int j = 0; j < 2; ++j)
      gload_lds16(Gb + bOff[j] + sh, (char*)Bs + (j * 32 + wv * 8) * 128);
    __syncthreads();
    bf16x8 af[2][4], bfv[2][2];
    #pragma unroll
    for (int kk = 0; kk < 2; ++kk) {
      #pragma unroll
      for (int i = 0; i < 4; ++i) {
        int rowa = wm * 64 + i * 16 + (l & 15);
        int offa = rowa * 128 + kk * 64 + ((l >> 4) * 16);
        offa ^= (rowa & 7) << 4;
        af[kk][i] = *(const bf16x8*)((const char*)As + offa);
      }
      #pragma unroll
      for (int i = 0; i < 2; ++i) {
        int rowb = wn * 32 + i * 16 + (l & 15);
        int offb = rowb * 128 + kk * 64 + ((l >> 4) * 16);
        offb ^= (rowb & 7) << 4;
        bfv[kk][i] = *(const bf16x8*)((const char*)Bs + offb);
      }
    }
    #pragma unroll
    for (int kk = 0; kk < 2; ++kk)
      #pragma unroll
      for (int mi = 0; mi < 4; ++mi)
        #pragma unroll
        for (int nj = 0; nj < 2; ++nj)
          acc[mi][nj] = __builtin_amdgcn_mfma_f32_16x16x32_bf16(
              af[kk][mi], bfv[kk][nj], acc[mi][nj], 0, 0, 0);
    __syncthreads();
  }

  // C/D layout: col=lane&15 (n), row=(lane>>4)*4+reg (co)
  bf16* op = Opart + (long)kq * CCH * NDIM;
  #pragma unroll
  for (int nj = 0; nj < 2; ++nj) {
    int nn = n0 + wn * 32 + nj * 16 + (l & 15);
    #pragma unroll
    for (int mi = 0; mi < 4; ++mi) {
      #pragma unroll
      for (int rr = 0; rr < 4; ++rr) {
        int co = co0 + wm * 64 + mi * 16 + (l >> 4) * 4 + rr;
        op[(long)co * NDIM + nn] = (bf16)acc[mi][nj][rr];
      }
    }
  }
}

// ---- epilogue: out[s][co][pq] = (sum_kq Opart + b[co]*BF(s,p,q)) * fin
// Each block covers ONE s; 16 threads build BF[16] in LDS once.
__global__ __launch_bounds__(256) void epi_kernel(const bf16* __restrict__ Opart,
                                                  const float* __restrict__ bb,
                                                  const float* __restrict__ cb,
                                                  float* __restrict__ out) {
  __shared__ float bfl[16];
  int bid = blockIdx.x;
  int t = threadIdx.x;
  int s = bid >> 3;                          // 8 blocks per s
  if (t < 16) {
    int p = t >> 2;
    int q = t & 3;
    float acc = 0.f;
    #pragma unroll
    for (int i = 0; i < 3; ++i) {
      int n = i * 64 + s;
      acc += axis_sum(bb[n * 4 + 1], bb[n * 4 + 3], p) *
             axis_sum(bb[n * 4 + 0], bb[n * 4 + 2], q);
    }
    bfl[t] = acc;
  }
  __syncthreads();
  int base = (bid * 256 + t) * 4;            // = s*8192 + co*16 + p*4
  int co = (base >> 4) & 511;
  int p = (base >> 2) & 3;
  long osrc = (long)co * NDIM + s * 16 + p * 4;
  f32x4 v = {0.f, 0.f, 0.f, 0.f};
  #pragma unroll
  for (int kq = 0; kq < KQ; ++kq) {
    bf16x4 o = *(const bf16x4*)(Opart + (long)kq * CCH * NDIM + osrc);
    #pragma unroll
    for (int j = 0; j < 4; ++j) v[j] += (float)o[j];
  }
  f32x4 bf4 = {bfl[p * 4 + 0], bfl[p * 4 + 1], bfl[p * 4 + 2], bfl[p * 4 + 3]};
  const float fin = 1.f / (3.f * 512.f * 16.f);
  v = (v + cb[co] * bf4) * fin;
  *(f32x4*)(out + base) = v;
}

extern "C" void kernel_launch(void* const* d_in, const int* in_sizes, int n_in,
                              void* d_out, int out_size, void* d_ws, size_t ws_size,
                              hipStream_t stream) {
  const float* feat = (const float*)d_in[0];
  const float* bb = (const float*)d_in[1];
  const float* cw = (const float*)d_in[2];
  const float* cb = (const float*)d_in[3];
  float* out = (float*)d_out;

  const size_t WB_BYTES = (size_t)CCH * 9 * CCH * 2;            //   4,718,592
  const size_t GB_BYTES = (size_t)NDIM * KDIM * 2;              //   9,437,184
  const size_t OP_BYTES = (size_t)KQ * CCH * NDIM * 2;          //   8,388,608
  if (ws_size < WB_BYTES + GB_BYTES + OP_BYTES) return;

  char* ws = (char*)d_ws;
  bf16* Wb = (bf16*)ws;
  bf16* Gb = (bf16*)(ws + WB_BYTES);
  bf16* Opart = (bf16*)(ws + WB_BYTES + GB_BYTES);

  hipLaunchKernelGGL(pool_feat_kernel, dim3(POOLBLKS + CCH), dim3(256), 0, stream,
                     feat, bb, cw, Wb, Gb);
  hipLaunchKernelGGL(gemm_kernel, dim3(512), dim3(256), 0, stream, Wb, Gb, Opart);
  hipLaunchKernelGGL(epi_kernel, dim3(512), dim3(256), 0, stream, Opart, bb, cb, out);
}